// Round 4
// baseline (348.763 us; speedup 1.0000x reference)
//
#include <hip/hip_runtime.h>
#include <stdint.h>

// Gator: logic-gate network forward, bit-packed over batch.
// Round-4 structure: 512 blocks x 1024 threads = 2 blocks/CU. Block pair
// (bg,0),(bg,1) redundantly packs x and runs the 8 gate rows for batch group
// bg (cheap, LLC/L2-fed), then each unpacks HALF the 9216 columns. The
// co-resident partner block keeps the store pipe busy while this block sits
// in its barriered pack/gate phases -> overlap the last ~10us of serial work.
// Output stores are nontemporal (pure streaming, no reuse).
// HBM floor: 302MB write + 33.5MB read ~= 53us @ 6.3TB/s.

constexpr int B    = 8192;
constexpr int W0   = 1024;
constexpr int R    = 8;
constexpr int G    = 1024;
constexpr int WTOT = W0 + R * G;   // 9216
constexpr int BPB  = 32;           // batch bits per block
constexpr int HALFW = WTOT / 2;    // 4608 columns unpacked per block

typedef float vfloat4 __attribute__((ext_vector_type(4)));

__launch_bounds__(1024, 2)
__global__ void gator_fused(const float* __restrict__ x,
                            const float* __restrict__ gates,
                            const int*   __restrict__ choices,
                            float*       __restrict__ out) {
    __shared__ uint32_t cols[WTOT];      // bit b of cols[w] = (batch b0+b, col w)

    const int tid   = threadIdx.x;
    const int lane  = tid & 63;
    const int wv    = tid >> 6;          // wave id 0..15
    const int bg    = blockIdx.x >> 1;   // batch group 0..255
    const int chalf = blockIdx.x & 1;    // which column half this block unpacks
    const int half  = lane >> 5;         // 0: lanes 0-31, 1: lanes 32-63
    const int row   = bg * BPB + (lane & 31);

    // ---- Phase A: pack x[32 rows][1024 cols] into bit columns ----
    // Wave wv covers cols [wv*64, wv*64+64); 8 cols per iteration via ballot.
    {
        const float4* xrow = (const float4*)(x + (size_t)row * W0);
        #pragma unroll
        for (int it = 0; it < 8; ++it) {
            int c = wv * 64 + it * 8 + half * 4;
            float4 v = xrow[c >> 2];
            unsigned long long m0 = __ballot(v.x != 0.0f);
            unsigned long long m1 = __ballot(v.y != 0.0f);
            unsigned long long m2 = __ballot(v.z != 0.0f);
            unsigned long long m3 = __ballot(v.w != 0.0f);
            if ((lane & 31) == 0) {      // lane 0 -> cols c..c+3, lane 32 -> c+4..c+7
                int s = half * 32;
                cols[c + 0] = (uint32_t)(m0 >> s);
                cols[c + 1] = (uint32_t)(m1 >> s);
                cols[c + 2] = (uint32_t)(m2 >> s);
                cols[c + 3] = (uint32_t)(m3 >> s);
            }
        }
    }
    __syncthreads();

    // ---- Phase B: 8 gate rows, one gate per thread per row ----
    {
        const int2*   ch2 = (const int2*)choices;   // [R*G] index pairs
        const float4* g4  = (const float4*)gates;   // [R*G] truth tables
        for (int r = 0; r < R; ++r) {
            int2     ch = ch2[r * G + tid];
            uint32_t a  = cols[ch.x];
            uint32_t b  = cols[ch.y];
            float4   lt = g4[r * G + tid];
            uint32_t o = 0u;
            o |= (lt.x != 0.0f) ? (~a & ~b) : 0u;   // a=0,b=0
            o |= (lt.y != 0.0f) ? (~a &  b) : 0u;   // a=0,b=1
            o |= (lt.z != 0.0f) ? ( a & ~b) : 0u;   // a=1,b=0
            o |= (lt.w != 0.0f) ? ( a &  b) : 0u;   // a=1,b=1
            cols[W0 + r * G + tid] = o;
            __syncthreads();
        }
    }

    // ---- Phase C: unpack this block's half of the columns ----
    // Thread t owns cols cbase + {t*4, t*4+4096}; 32 batch bits each;
    // coalesced nontemporal float4 stores (1KB/wave contiguous).
    const int cbase = chalf * HALFW;
    for (int w = tid * 4; w < HALFW; w += 4096) {
        uint4 c = *(const uint4*)&cols[cbase + w];
        float* orow = out + (size_t)bg * BPB * WTOT + cbase + w;
        #pragma unroll
        for (int b = 0; b < BPB; ++b) {
            vfloat4 v;
            v.x = (float)((c.x >> b) & 1u);
            v.y = (float)((c.y >> b) & 1u);
            v.z = (float)((c.z >> b) & 1u);
            v.w = (float)((c.w >> b) & 1u);
            __builtin_nontemporal_store(v, (vfloat4*)(orow + (size_t)b * WTOT));
        }
    }
}

extern "C" void kernel_launch(void* const* d_in, const int* in_sizes, int n_in,
                              void* d_out, int out_size, void* d_ws, size_t ws_size,
                              hipStream_t stream) {
    const float* x       = (const float*)d_in[0];
    const float* gates   = (const float*)d_in[1];
    const int*   choices = (const int*)d_in[2];
    float*       out     = (float*)d_out;
    (void)d_ws; (void)ws_size;

    gator_fused<<<dim3((B / BPB) * 2), dim3(1024), 0, stream>>>(x, gates, choices, out);
}

// Round 5
// 328.807 us; speedup vs baseline: 1.0607x; 1.0607x over previous
//
#include <hip/hip_runtime.h>
#include <stdint.h>

// Gator: logic-gate network forward, bit-packed over batch. Single fused
// kernel, 256 blocks x 1024 threads, 1 block/CU (R3 structure — the measured
// winner; R4's 2-blocks/CU redundant-compute variant regressed).
//
// This round: (1) prefetch all 8 rows' choice pairs + truth tables into
// registers BEFORE the barriered phase (compiler can't hoist globals across
// __syncthreads; removes ~8x200cyc L2 latency from the serial chain),
// (2) nontemporal streaming stores for the 302MB output.
// Kernel HBM floor: 302MB write + 33.5MB read ~= 53us @ 6.3TB/s.

constexpr int B    = 8192;
constexpr int W0   = 1024;
constexpr int R    = 8;
constexpr int G    = 1024;
constexpr int WTOT = W0 + R * G;   // 9216
constexpr int BPB  = 32;           // batch bits per block

typedef float vfloat4 __attribute__((ext_vector_type(4)));

__launch_bounds__(1024, 1)
__global__ void gator_fused(const float* __restrict__ x,
                            const float* __restrict__ gates,
                            const int*   __restrict__ choices,
                            float*       __restrict__ out) {
    __shared__ uint32_t cols[WTOT];      // bit b of cols[w] = (batch b0+b, col w)

    const int tid  = threadIdx.x;
    const int lane = tid & 63;
    const int wv   = tid >> 6;           // wave id 0..15
    const int bg   = blockIdx.x;
    const int half = lane >> 5;          // 0: lanes 0-31, 1: lanes 32-63
    const int row  = bg * BPB + (lane & 31);

    // ---- Prefetch gate metadata for all 8 rows into registers ----
    // Thread tid owns gate (r, tid) for every row r. Issue these loads up
    // front so they overlap the pack phase and never sit on the barrier chain.
    const int2*   ch2 = (const int2*)choices;    // [R*G] index pairs
    const float4* g4  = (const float4*)gates;    // [R*G] truth tables
    int2     ch[R];
    uint32_t tt[R];                              // 4-bit truth table mask
    #pragma unroll
    for (int r = 0; r < R; ++r) {
        ch[r] = ch2[r * G + tid];
        float4 lt = g4[r * G + tid];
        tt[r] = (lt.x != 0.0f ? 1u : 0u) | (lt.y != 0.0f ? 2u : 0u) |
                (lt.z != 0.0f ? 4u : 0u) | (lt.w != 0.0f ? 8u : 0u);
    }

    // ---- Phase A: pack x[32 rows][1024 cols] into bit columns ----
    // Wave wv covers cols [wv*64, wv*64+64); 8 cols per iteration via ballot.
    {
        const float4* xrow = (const float4*)(x + (size_t)row * W0);
        #pragma unroll
        for (int it = 0; it < 8; ++it) {
            int c = wv * 64 + it * 8 + half * 4;
            float4 v = xrow[c >> 2];
            unsigned long long m0 = __ballot(v.x != 0.0f);
            unsigned long long m1 = __ballot(v.y != 0.0f);
            unsigned long long m2 = __ballot(v.z != 0.0f);
            unsigned long long m3 = __ballot(v.w != 0.0f);
            if ((lane & 31) == 0) {      // lane 0 -> cols c..c+3, lane 32 -> c+4..c+7
                int s = half * 32;
                cols[c + 0] = (uint32_t)(m0 >> s);
                cols[c + 1] = (uint32_t)(m1 >> s);
                cols[c + 2] = (uint32_t)(m2 >> s);
                cols[c + 3] = (uint32_t)(m3 >> s);
            }
        }
    }
    __syncthreads();

    // ---- Phase B: 8 gate rows, one gate per thread per row ----
    // All operands except the two LDS gathers are already in registers.
    #pragma unroll
    for (int r = 0; r < R; ++r) {
        uint32_t a = cols[ch[r].x];
        uint32_t b = cols[ch[r].y];
        uint32_t m0 = 0u - (tt[r] & 1u);          // broadcast each LUT bit
        uint32_t m1 = 0u - ((tt[r] >> 1) & 1u);
        uint32_t m2 = 0u - ((tt[r] >> 2) & 1u);
        uint32_t m3 = 0u - ((tt[r] >> 3) & 1u);
        uint32_t o = (m0 & ~a & ~b) | (m1 & ~a & b) | (m2 & a & ~b) | (m3 & a & b);
        cols[W0 + r * G + tid] = o;
        __syncthreads();
    }

    // ---- Phase C: unpack all 9216 columns to float32 ----
    // Thread t owns cols {4t, 4t+4096, 4t+8192}; 32 batch bits each;
    // coalesced nontemporal float4 stores (1KB/wave contiguous).
    for (int w = tid * 4; w < WTOT; w += 4096) {
        uint4 c = *(const uint4*)&cols[w];
        float* orow = out + (size_t)bg * BPB * WTOT + w;
        #pragma unroll
        for (int b = 0; b < BPB; ++b) {
            vfloat4 v;
            v.x = (float)((c.x >> b) & 1u);
            v.y = (float)((c.y >> b) & 1u);
            v.z = (float)((c.z >> b) & 1u);
            v.w = (float)((c.w >> b) & 1u);
            __builtin_nontemporal_store(v, (vfloat4*)(orow + (size_t)b * WTOT));
        }
    }
}

extern "C" void kernel_launch(void* const* d_in, const int* in_sizes, int n_in,
                              void* d_out, int out_size, void* d_ws, size_t ws_size,
                              hipStream_t stream) {
    const float* x       = (const float*)d_in[0];
    const float* gates   = (const float*)d_in[1];
    const int*   choices = (const int*)d_in[2];
    float*       out     = (float*)d_out;
    (void)d_ws; (void)ws_size;

    gator_fused<<<dim3(B / BPB), dim3(1024), 0, stream>>>(x, gates, choices, out);
}